// Round 1
// baseline (3765.315 us; speedup 1.0000x reference)
//
#include <hip/hip_runtime.h>
#include <cfloat>
#include <cmath>

#define R_ROIS 512
#define NCLS 11
#define FEAT_C 512
#define FEAT_H 37
#define FEAT_W 50
#define POOLSZ 7
#define POOL_DIM (FEAT_C * POOLSZ * POOLSZ) /* 25088 */
#define FC_DIM 4096
#define IMG_Hf 600.0f
#define IMG_Wf 800.0f
#define SPATIAL_SCALE 0.0625f
#define NMS_THR 0.3f
#define SCORE_THR 0.05f

#define OUT_BBOX_OFF 0                     /* 512*44 = 22528 */
#define OUT_PROB_OFF (R_ROIS * NCLS * 4)   /* 22528 */
#define OUT_KEEP_OFF (OUT_PROB_OFF + R_ROIS * NCLS) /* 28160 */

// ---------------------------------------------------------------- ROI pool
__global__ __launch_bounds__(256) void roi_pool_kernel(
    const float* __restrict__ feat, const float* __restrict__ rois,
    const int* __restrict__ roi_idx, float* __restrict__ pool) {
  int r = blockIdx.x;
  // rois stored (y1,x1,y2,x2); reference permutes to (x1,y1,x2,y2)
  float y1 = rois[r * 4 + 0], x1 = rois[r * 4 + 1];
  float y2 = rois[r * 4 + 2], x2 = rois[r * 4 + 3];
  float sw = rintf(x1 * SPATIAL_SCALE), ew = rintf(x2 * SPATIAL_SCALE);
  float sh = rintf(y1 * SPATIAL_SCALE), eh = rintf(y2 * SPATIAL_SCALE);
  float rw = fmaxf(ew - sw + 1.0f, 1.0f);
  float rh = fmaxf(eh - sh + 1.0f, 1.0f);
  int hs[POOLSZ], he[POOLSZ], wsA[POOLSZ], weA[POOLSZ];
#pragma unroll
  for (int p = 0; p < POOLSZ; ++p) {
    float fp = (float)p;
    hs[p] = (int)fminf(fmaxf(floorf(fp * rh / 7.0f) + sh, 0.0f), (float)FEAT_H);
    he[p] = (int)fminf(fmaxf(ceilf((fp + 1.0f) * rh / 7.0f) + sh, 0.0f), (float)FEAT_H);
    wsA[p] = (int)fminf(fmaxf(floorf(fp * rw / 7.0f) + sw, 0.0f), (float)FEAT_W);
    weA[p] = (int)fminf(fmaxf(ceilf((fp + 1.0f) * rw / 7.0f) + sw, 0.0f), (float)FEAT_W);
  }
  const float* f = feat + (size_t)roi_idx[r] * FEAT_C * FEAT_H * FEAT_W;
  for (int idx = threadIdx.x; idx < POOL_DIM; idx += 256) {
    int c = idx / 49;
    int rem = idx - c * 49;
    int p = rem / 7;   // h bin
    int q = rem - p * 7; // w bin
    float v = 0.0f;
    if (he[p] > hs[p] && weA[q] > wsA[q]) {
      v = -FLT_MAX;
      const float* fc = f + (size_t)c * FEAT_H * FEAT_W;
      for (int y = hs[p]; y < he[p]; ++y)
        for (int x = wsA[q]; x < weA[q]; ++x)
          v = fmaxf(v, fc[y * FEAT_W + x]);
    }
    pool[(size_t)r * POOL_DIM + idx] = v;
  }
}

// ---------------------------------------------------------------- fp32 GEMM
// C[M,N] = act(A[M,K] @ B[K,N] + bias[N]); BM=BN=64, BK=16, 256 thr, 4x4/thr
__global__ __launch_bounds__(256) void gemm_bias_relu(
    const float* __restrict__ A, const float* __restrict__ B,
    const float* __restrict__ bias, float* __restrict__ C, int M, int N, int K,
    int do_relu) {
  __shared__ float As[16][65];  // [k][m], padded
  __shared__ float Bs[16][64];  // [k][n]
  int tid = threadIdx.x;
  int bm = blockIdx.y * 64;
  int bn = blockIdx.x * 64;
  int ty = tid / 16, tx = tid % 16;
  int arow = tid / 4;
  int acol4 = (tid % 4) * 4;
  int brow = tid / 16;
  int bcol4 = (tid % 16) * 4;
  float acc[4][4] = {};
  for (int k0 = 0; k0 < K; k0 += 16) {
    __syncthreads();
    float4 av = *(const float4*)(A + (size_t)(bm + arow) * K + k0 + acol4);
    As[acol4 + 0][arow] = av.x;
    As[acol4 + 1][arow] = av.y;
    As[acol4 + 2][arow] = av.z;
    As[acol4 + 3][arow] = av.w;
    float4 bv = *(const float4*)(B + (size_t)(k0 + brow) * N + bn + bcol4);
    *(float4*)(&Bs[brow][bcol4]) = bv;
    __syncthreads();
#pragma unroll
    for (int kk = 0; kk < 16; ++kk) {
      float a[4], b[4];
#pragma unroll
      for (int i = 0; i < 4; ++i) a[i] = As[kk][ty + 16 * i];
#pragma unroll
      for (int j = 0; j < 4; ++j) b[j] = Bs[kk][tx + 16 * j];
#pragma unroll
      for (int i = 0; i < 4; ++i)
#pragma unroll
        for (int j = 0; j < 4; ++j) acc[i][j] += a[i] * b[j];
    }
  }
#pragma unroll
  for (int i = 0; i < 4; ++i) {
    int row = bm + ty + 16 * i;
#pragma unroll
    for (int j = 0; j < 4; ++j) {
      int col = bn + tx + 16 * j;
      float v = acc[i][j] + bias[col];
      if (do_relu) v = fmaxf(v, 0.0f);
      C[(size_t)row * N + col] = v;
    }
  }
}

// ---------------------------------------------------------------- head
// per-roi: fc7 @ Wloc/+bloc, fc7 @ Wscore/+bscore, box decode, softmax
__global__ __launch_bounds__(256) void head_kernel(
    const float* __restrict__ fc7, const float* __restrict__ Wloc,
    const float* __restrict__ bloc, const float* __restrict__ Wscore,
    const float* __restrict__ bscore, const float* __restrict__ rois,
    float* __restrict__ out) {
  __shared__ float row[FC_DIM];
  __shared__ float outv[64];
  int r = blockIdx.x;
  int tid = threadIdx.x;
  for (int k = tid; k < FC_DIM; k += 256) row[k] = fc7[(size_t)r * FC_DIM + k];
  __syncthreads();
  int wave = tid >> 6, lane = tid & 63;
  for (int o = wave; o < 55; o += 4) {
    float partial = 0.0f;
    if (o < 44) {
      for (int k = lane; k < FC_DIM; k += 64)
        partial += row[k] * Wloc[(size_t)k * 44 + o];
    } else {
      int j = o - 44;
      for (int k = lane; k < FC_DIM; k += 64)
        partial += row[k] * Wscore[(size_t)k * 11 + j];
    }
#pragma unroll
    for (int off = 32; off; off >>= 1) partial += __shfl_down(partial, off);
    if (lane == 0) outv[o] = partial;
  }
  __syncthreads();
  if (tid == 0) {
    // softmax over 11 scores
    float s[NCLS];
    float m = -FLT_MAX;
#pragma unroll
    for (int j = 0; j < NCLS; ++j) {
      s[j] = outv[44 + j] + bscore[j];
      m = fmaxf(m, s[j]);
    }
    float sum = 0.0f;
#pragma unroll
    for (int j = 0; j < NCLS; ++j) {
      s[j] = expf(s[j] - m);
      sum += s[j];
    }
    float inv = 1.0f / sum;
#pragma unroll
    for (int j = 0; j < NCLS; ++j) out[OUT_PROB_OFF + r * NCLS + j] = s[j] * inv;
    // boxes (SCALE = 1)
    float y1 = rois[r * 4 + 0], x1 = rois[r * 4 + 1];
    float y2 = rois[r * 4 + 2], x2 = rois[r * 4 + 3];
    float shh = y2 - y1, sww = x2 - x1;
    float cy = y1 + 0.5f * shh, cx = x1 + 0.5f * sww;
    const float STD[4] = {0.1f, 0.1f, 0.2f, 0.2f};
    for (int c = 0; c < NCLS; ++c) {
      float l0 = (outv[c * 4 + 0] + bloc[c * 4 + 0]) * STD[0];
      float l1 = (outv[c * 4 + 1] + bloc[c * 4 + 1]) * STD[1];
      float l2 = (outv[c * 4 + 2] + bloc[c * 4 + 2]) * STD[2];
      float l3 = (outv[c * 4 + 3] + bloc[c * 4 + 3]) * STD[3];
      float ncy = l0 * shh + cy, ncx = l1 * sww + cx;
      float nh = expf(l2) * shh, nw = expf(l3) * sww;
      out[r * 44 + c * 4 + 0] = fminf(fmaxf(ncy - 0.5f * nh, 0.0f), IMG_Hf);
      out[r * 44 + c * 4 + 1] = fminf(fmaxf(ncx - 0.5f * nw, 0.0f), IMG_Wf);
      out[r * 44 + c * 4 + 2] = fminf(fmaxf(ncy + 0.5f * nh, 0.0f), IMG_Hf);
      out[r * 44 + c * 4 + 3] = fminf(fmaxf(ncx + 0.5f * nw, 0.0f), IMG_Wf);
    }
  }
}

// ---------------------------------------------------------------- NMS
// one block per class (1..10); 512 threads; bitonic sort (stable via idx
// tie-break, matches stable argsort of where(valid,-score,inf)) + greedy.
__device__ __forceinline__ bool key_lt(float ka, int ia, float kb, int ib) {
  return (ka < kb) || (ka == kb && ia < ib);
}

__global__ __launch_bounds__(512) void nms_kernel(
    const float* __restrict__ cls_bbox, const float* __restrict__ prob,
    float* __restrict__ keep_out) {
  int c = blockIdx.x + 1;  // skip background class 0
  int tid = threadIdx.x;
  __shared__ float skey[512];
  __shared__ int sidx[512];
  __shared__ float by1[512], bx1[512], by2[512], bx2[512], sarea[512];
  __shared__ int skeep[512];
  float s = prob[tid * NCLS + c];
  skey[tid] = (s > SCORE_THR) ? -s : INFINITY;
  sidx[tid] = tid;
  // bitonic sort ascending by (key, idx)
  for (int k = 2; k <= 512; k <<= 1) {
    for (int j = k >> 1; j > 0; j >>= 1) {
      __syncthreads();
      int ixj = tid ^ j;
      if (ixj > tid) {
        float k1 = skey[tid], k2 = skey[ixj];
        int i1 = sidx[tid], i2 = sidx[ixj];
        bool up = ((tid & k) == 0);
        bool do_swap = up ? key_lt(k2, i2, k1, i1) : key_lt(k1, i1, k2, i2);
        if (do_swap) {
          skey[tid] = k2; skey[ixj] = k1;
          sidx[tid] = i2; sidx[ixj] = i1;
        }
      }
    }
  }
  __syncthreads();
  {
    int r = sidx[tid];
    float yy1 = cls_bbox[r * 44 + c * 4 + 0];
    float xx1 = cls_bbox[r * 44 + c * 4 + 1];
    float yy2 = cls_bbox[r * 44 + c * 4 + 2];
    float xx2 = cls_bbox[r * 44 + c * 4 + 3];
    by1[tid] = yy1; bx1[tid] = xx1; by2[tid] = yy2; bx2[tid] = xx2;
    sarea[tid] = (yy2 - yy1) * (xx2 - xx1);
    skeep[tid] = (skey[tid] != INFINITY) ? 1 : 0;
  }
  // greedy suppression in sorted order
  for (int i = 0; i < 511; ++i) {
    __syncthreads();
    if (!skeep[i]) continue;
    int j = tid;
    if (j > i && skeep[j]) {
      float ty = fmaxf(by1[i], by1[j]);
      float tx = fmaxf(bx1[i], bx1[j]);
      float byy = fminf(by2[i], by2[j]);
      float bxx = fminf(bx2[i], bx2[j]);
      float hh = fmaxf(byy - ty, 0.0f);
      float ww = fmaxf(bxx - tx, 0.0f);
      float inter = hh * ww;
      float iou = inter / (sarea[i] + sarea[j] - inter);
      if (iou > NMS_THR) skeep[j] = 0;
    }
  }
  __syncthreads();
  keep_out[(size_t)(c - 1) * R_ROIS + sidx[tid]] = skeep[tid] ? 1.0f : 0.0f;
}

// ---------------------------------------------------------------- launch
extern "C" void kernel_launch(void* const* d_in, const int* in_sizes, int n_in,
                              void* d_out, int out_size, void* d_ws,
                              size_t ws_size, hipStream_t stream) {
  const float* h = (const float*)d_in[0];
  const float* rois = (const float*)d_in[1];
  const int* roi_indices = (const int*)d_in[2];
  const float* W1 = (const float*)d_in[3];
  const float* b1 = (const float*)d_in[4];
  const float* W2 = (const float*)d_in[5];
  const float* b2 = (const float*)d_in[6];
  const float* Wloc = (const float*)d_in[7];
  const float* bloc = (const float*)d_in[8];
  const float* Wscore = (const float*)d_in[9];
  const float* bscore = (const float*)d_in[10];
  float* out = (float*)d_out;

  float* ws = (float*)d_ws;
  float* pool = ws;                                  // 512*25088 floats
  float* fc = pool + (size_t)R_ROIS * POOL_DIM;      // 512*4096
  float* fc7 = fc + (size_t)R_ROIS * FC_DIM;         // 512*4096

  roi_pool_kernel<<<R_ROIS, 256, 0, stream>>>(h, rois, roi_indices, pool);
  gemm_bias_relu<<<dim3(FC_DIM / 64, R_ROIS / 64), 256, 0, stream>>>(
      pool, W1, b1, fc, R_ROIS, FC_DIM, POOL_DIM, 1);
  gemm_bias_relu<<<dim3(FC_DIM / 64, R_ROIS / 64), 256, 0, stream>>>(
      fc, W2, b2, fc7, R_ROIS, FC_DIM, FC_DIM, 1);
  head_kernel<<<R_ROIS, 256, 0, stream>>>(fc7, Wloc, bloc, Wscore, bscore,
                                          rois, out);
  nms_kernel<<<10, 512, 0, stream>>>(out, out + OUT_PROB_OFF,
                                     out + OUT_KEEP_OFF);
}

// Round 2
// 1496.546 us; speedup vs baseline: 2.5160x; 2.5160x over previous
//
#include <hip/hip_runtime.h>
#include <cfloat>
#include <cmath>
#include <stdint.h>

#define R_ROIS 512
#define NCLS 11
#define FEAT_C 512
#define FEAT_H 37
#define FEAT_W 50
#define POOLSZ 7
#define POOL_DIM (FEAT_C * POOLSZ * POOLSZ) /* 25088 */
#define FC_DIM 4096
#define IMG_Hf 600.0f
#define IMG_Wf 800.0f
#define SPATIAL_SCALE 0.0625f
#define NMS_THR 0.3f
#define SCORE_THR 0.05f

#define OUT_PROB_OFF (R_ROIS * NCLS * 4)
#define OUT_KEEP_OFF (OUT_PROB_OFF + R_ROIS * NCLS)

typedef __bf16 bf16;
typedef __attribute__((ext_vector_type(8))) __bf16 v8bf;
typedef __attribute__((ext_vector_type(4))) __bf16 v4bf;
typedef __attribute__((ext_vector_type(4))) float f32x4;
typedef unsigned int u32;

// generic -> addrspace pointers for global_load_lds (low 32 bits of a generic
// LDS pointer are the LDS offset; global generic == global address)
__device__ __forceinline__ void gload_lds16(const void* g, void* l) {
  __builtin_amdgcn_global_load_lds(
      (const __attribute__((address_space(1))) u32*)(uintptr_t)g,
      (__attribute__((address_space(3))) u32*)(uintptr_t)l, 16, 0, 0);
}

// ---------------------------------------------------------------- ROI pool
__global__ __launch_bounds__(256) void roi_pool_kernel(
    const float* __restrict__ feat, const float* __restrict__ rois,
    const int* __restrict__ roi_idx, bf16* __restrict__ pool) {
  int r = blockIdx.x;
  float y1 = rois[r * 4 + 0], x1 = rois[r * 4 + 1];
  float y2 = rois[r * 4 + 2], x2 = rois[r * 4 + 3];
  float sw = rintf(x1 * SPATIAL_SCALE), ew = rintf(x2 * SPATIAL_SCALE);
  float sh = rintf(y1 * SPATIAL_SCALE), eh = rintf(y2 * SPATIAL_SCALE);
  float rw = fmaxf(ew - sw + 1.0f, 1.0f);
  float rh = fmaxf(eh - sh + 1.0f, 1.0f);
  int hs[POOLSZ], he[POOLSZ], wsA[POOLSZ], weA[POOLSZ];
#pragma unroll
  for (int p = 0; p < POOLSZ; ++p) {
    float fp = (float)p;
    hs[p] = (int)fminf(fmaxf(floorf(fp * rh / 7.0f) + sh, 0.0f), (float)FEAT_H);
    he[p] = (int)fminf(fmaxf(ceilf((fp + 1.0f) * rh / 7.0f) + sh, 0.0f), (float)FEAT_H);
    wsA[p] = (int)fminf(fmaxf(floorf(fp * rw / 7.0f) + sw, 0.0f), (float)FEAT_W);
    weA[p] = (int)fminf(fmaxf(ceilf((fp + 1.0f) * rw / 7.0f) + sw, 0.0f), (float)FEAT_W);
  }
  const float* f = feat + (size_t)roi_idx[r] * FEAT_C * FEAT_H * FEAT_W;
  for (int idx = threadIdx.x; idx < POOL_DIM; idx += 256) {
    int c = idx / 49;
    int rem = idx - c * 49;
    int p = rem / 7;
    int q = rem - p * 7;
    float v = 0.0f;
    if (he[p] > hs[p] && weA[q] > wsA[q]) {
      v = -FLT_MAX;
      const float* fc = f + (size_t)c * FEAT_H * FEAT_W;
      for (int y = hs[p]; y < he[p]; ++y)
        for (int x = wsA[q]; x < weA[q]; ++x)
          v = fmaxf(v, fc[y * FEAT_W + x]);
    }
    pool[(size_t)r * POOL_DIM + idx] = (bf16)v;
  }
}

// ------------------------------------------------- head weight transpose
// WT[o][k], o<44 from Wloc[k][o], o>=44 from Wscore[k][o-44]
__global__ __launch_bounds__(256) void whead_transpose(
    const float* __restrict__ Wloc, const float* __restrict__ Wscore,
    float* __restrict__ WT) {
  int o = blockIdx.x;
  for (int k = threadIdx.x; k < FC_DIM; k += 256) {
    float v = (o < 44) ? Wloc[(size_t)k * 44 + o]
                       : Wscore[(size_t)k * 11 + (o - 44)];
    WT[(size_t)o * FC_DIM + k] = v;
  }
}

// ---------------------------------------------------------------- MFMA GEMM
// A: bf16 [512, K] row-major. B: fp32 [K, 4096] row-major (converted to bf16
// during LDS staging, stored transposed [n][k] with +8 bf16 row pad).
// Writes fp32 partials part[s][512][4096]. Grid (4=bm, 32=bn, S).
__global__ __launch_bounds__(256) void gemm_mfma(
    const bf16* __restrict__ A, const float* __restrict__ B,
    float* __restrict__ part, int K, int Kper) {
  __shared__ __align__(16) bf16 As[128 * 32];   // [m][k], unpadded (DMA dest)
  __shared__ __align__(16) bf16 Bs[128 * 40];   // [n][k], stride 40 (pad 8)
  int tid = threadIdx.x;
  int bm = blockIdx.x * 128;
  int bn = blockIdx.y * 128;
  int s = blockIdx.z;
  int kbeg = s * Kper;
  int kend = kbeg + Kper;
  int lane = tid & 63;
  int wave = tid >> 6;
  int wm = (wave >> 1) * 64;
  int wn = (wave & 1) * 64;

  f32x4 acc[4][4];
#pragma unroll
  for (int i = 0; i < 4; ++i)
#pragma unroll
    for (int j = 0; j < 4; ++j) acc[i][j] = (f32x4){0.f, 0.f, 0.f, 0.f};

  // A staging: 2 issues of 256 lanes x 16B; row-major [m][k] contiguous in LDS
  int arow = tid >> 2;
  int acol = (tid & 3) * 8;
  const bf16* Ag0 = A + (size_t)(bm + arow) * K + acol;
  const bf16* Ag1 = A + (size_t)(bm + 64 + arow) * K + acol;
  bf16* Ad0 = As + tid * 8;
  bf16* Ad1 = As + 2048 + tid * 8;

  // B staging: thread covers n=tid&127, k-range kh..kh+15
  int nB = tid & 127;
  int khB = (tid >> 7) * 16;
  const float* Bg = B + (size_t)khB * FC_DIM + bn + nB;
  bf16* Bd = Bs + nB * 40 + khB;

  for (int k0 = kbeg; k0 < kend; k0 += 32) {
    __syncthreads();  // LDS free before overwrite
    gload_lds16(Ag0 + k0, Ad0);
    gload_lds16(Ag1 + k0, Ad1);
    const float* bp = Bg + (size_t)k0 * FC_DIM;
    float bv[16];
#pragma unroll
    for (int j = 0; j < 16; ++j) bv[j] = bp[(size_t)j * FC_DIM];
    v8bf blo, bhi;
#pragma unroll
    for (int j = 0; j < 8; ++j) blo[j] = (bf16)bv[j];
#pragma unroll
    for (int j = 0; j < 8; ++j) bhi[j] = (bf16)bv[8 + j];
    *(v8bf*)(Bd) = blo;
    *(v8bf*)(Bd + 8) = bhi;
    __syncthreads();  // staging (incl. global_load_lds) visible

    v8bf af[4], bfr[4];
#pragma unroll
    for (int i = 0; i < 4; ++i)
      af[i] = *(const v8bf*)(As + (wm + i * 16 + (lane & 15)) * 32 +
                             (lane >> 4) * 8);
#pragma unroll
    for (int j = 0; j < 4; ++j)
      bfr[j] = *(const v8bf*)(Bs + (wn + j * 16 + (lane & 15)) * 40 +
                              (lane >> 4) * 8);
#pragma unroll
    for (int i = 0; i < 4; ++i)
#pragma unroll
      for (int j = 0; j < 4; ++j)
        acc[i][j] = __builtin_amdgcn_mfma_f32_16x16x32_bf16(af[i], bfr[j],
                                                            acc[i][j], 0, 0, 0);
  }

  // epilogue: C/D map col=lane&15, row=(lane>>4)*4+reg
  int cn = lane & 15;
  int rq = (lane >> 4) * 4;
  float* po = part + ((size_t)s * R_ROIS + bm + wm + rq) * FC_DIM + bn + wn + cn;
#pragma unroll
  for (int i = 0; i < 4; ++i)
#pragma unroll
    for (int r = 0; r < 4; ++r) {
      float* pr = po + (size_t)(i * 16 + r) * FC_DIM;
#pragma unroll
      for (int j = 0; j < 4; ++j) pr[j * 16] = acc[i][j][r];
    }
}

// ------------------------------------------------- split-K reduce + bias+relu
__global__ __launch_bounds__(256) void reduce_bias_relu(
    const float* __restrict__ part, const float* __restrict__ bias, int S,
    bf16* __restrict__ out_bf, float* __restrict__ out_f32) {
  int idx = (blockIdx.x * 256 + threadIdx.x) * 4;  // over 512*4096
  f32x4 sum = *(const f32x4*)(part + idx);
  for (int s = 1; s < S; ++s)
    sum += *(const f32x4*)(part + (size_t)s * R_ROIS * FC_DIM + idx);
  int n = idx & (FC_DIM - 1);
  f32x4 b = *(const f32x4*)(bias + n);
  sum += b;
#pragma unroll
  for (int c = 0; c < 4; ++c) sum[c] = fmaxf(sum[c], 0.0f);
  *(f32x4*)(out_f32 + idx) = sum;
  v4bf h;
#pragma unroll
  for (int c = 0; c < 4; ++c) h[c] = (bf16)sum[c];
  *(v4bf*)(out_bf + idx) = h;
}

// ---------------------------------------------------------------- head
__global__ __launch_bounds__(256) void head_kernel(
    const float* __restrict__ fc7, const float* __restrict__ WT,
    const float* __restrict__ bloc, const float* __restrict__ bscore,
    const float* __restrict__ rois, float* __restrict__ out) {
  __shared__ float row[FC_DIM];
  __shared__ float outv[64];
  int r = blockIdx.x;
  int tid = threadIdx.x;
  for (int k = tid * 4; k < FC_DIM; k += 1024)
    *(float4*)(row + k) = *(const float4*)(fc7 + (size_t)r * FC_DIM + k);
  __syncthreads();
  int wave = tid >> 6, lane = tid & 63;
  for (int o = wave; o < 55; o += 4) {
    const float* w = WT + (size_t)o * FC_DIM;
    float p = 0.0f;
    for (int k = lane * 4; k < FC_DIM; k += 256) {
      float4 a = *(const float4*)(row + k);
      float4 b = *(const float4*)(w + k);
      p += a.x * b.x + a.y * b.y + a.z * b.z + a.w * b.w;
    }
#pragma unroll
    for (int off = 32; off; off >>= 1) p += __shfl_down(p, off);
    if (lane == 0) outv[o] = p;
  }
  __syncthreads();
  if (tid == 0) {
    float sarr[NCLS];
    float m = -FLT_MAX;
#pragma unroll
    for (int j = 0; j < NCLS; ++j) {
      sarr[j] = outv[44 + j] + bscore[j];
      m = fmaxf(m, sarr[j]);
    }
    float sum = 0.0f;
#pragma unroll
    for (int j = 0; j < NCLS; ++j) {
      sarr[j] = expf(sarr[j] - m);
      sum += sarr[j];
    }
    float inv = 1.0f / sum;
#pragma unroll
    for (int j = 0; j < NCLS; ++j)
      out[OUT_PROB_OFF + r * NCLS + j] = sarr[j] * inv;
    float y1 = rois[r * 4 + 0], x1 = rois[r * 4 + 1];
    float y2 = rois[r * 4 + 2], x2 = rois[r * 4 + 3];
    float shh = y2 - y1, sww = x2 - x1;
    float cy = y1 + 0.5f * shh, cx = x1 + 0.5f * sww;
    const float STD[4] = {0.1f, 0.1f, 0.2f, 0.2f};
    for (int c = 0; c < NCLS; ++c) {
      float l0 = (outv[c * 4 + 0] + bloc[c * 4 + 0]) * STD[0];
      float l1 = (outv[c * 4 + 1] + bloc[c * 4 + 1]) * STD[1];
      float l2 = (outv[c * 4 + 2] + bloc[c * 4 + 2]) * STD[2];
      float l3 = (outv[c * 4 + 3] + bloc[c * 4 + 3]) * STD[3];
      float ncy = l0 * shh + cy, ncx = l1 * sww + cx;
      float nh = expf(l2) * shh, nw = expf(l3) * sww;
      out[r * 44 + c * 4 + 0] = fminf(fmaxf(ncy - 0.5f * nh, 0.0f), IMG_Hf);
      out[r * 44 + c * 4 + 1] = fminf(fmaxf(ncx - 0.5f * nw, 0.0f), IMG_Wf);
      out[r * 44 + c * 4 + 2] = fminf(fmaxf(ncy + 0.5f * nh, 0.0f), IMG_Hf);
      out[r * 44 + c * 4 + 3] = fminf(fmaxf(ncx + 0.5f * nw, 0.0f), IMG_Wf);
    }
  }
}

// ---------------------------------------------------------------- NMS
__device__ __forceinline__ bool key_lt(float ka, int ia, float kb, int ib) {
  return (ka < kb) || (ka == kb && ia < ib);
}

__global__ __launch_bounds__(512) void nms_kernel(
    const float* __restrict__ cls_bbox, const float* __restrict__ prob,
    float* __restrict__ keep_out) {
  int c = blockIdx.x + 1;
  int tid = threadIdx.x;
  __shared__ float skey[512];
  __shared__ int sidx[512];
  __shared__ float by1[512], bx1[512], by2[512], bx2[512], sarea[512];
  __shared__ int skeep[512];
  float s = prob[tid * NCLS + c];
  skey[tid] = (s > SCORE_THR) ? -s : INFINITY;
  sidx[tid] = tid;
  for (int k = 2; k <= 512; k <<= 1) {
    for (int j = k >> 1; j > 0; j >>= 1) {
      __syncthreads();
      int ixj = tid ^ j;
      if (ixj > tid) {
        float k1 = skey[tid], k2 = skey[ixj];
        int i1 = sidx[tid], i2 = sidx[ixj];
        bool up = ((tid & k) == 0);
        bool do_swap = up ? key_lt(k2, i2, k1, i1) : key_lt(k1, i1, k2, i2);
        if (do_swap) {
          skey[tid] = k2; skey[ixj] = k1;
          sidx[tid] = i2; sidx[ixj] = i1;
        }
      }
    }
  }
  __syncthreads();
  {
    int r = sidx[tid];
    float yy1 = cls_bbox[r * 44 + c * 4 + 0];
    float xx1 = cls_bbox[r * 44 + c * 4 + 1];
    float yy2 = cls_bbox[r * 44 + c * 4 + 2];
    float xx2 = cls_bbox[r * 44 + c * 4 + 3];
    by1[tid] = yy1; bx1[tid] = xx1; by2[tid] = yy2; bx2[tid] = xx2;
    sarea[tid] = (yy2 - yy1) * (xx2 - xx1);
    skeep[tid] = (skey[tid] != INFINITY) ? 1 : 0;
  }
  for (int i = 0; i < 511; ++i) {
    __syncthreads();
    if (!skeep[i]) continue;
    int j = tid;
    if (j > i && skeep[j]) {
      float ty = fmaxf(by1[i], by1[j]);
      float tx = fmaxf(bx1[i], bx1[j]);
      float byy = fminf(by2[i], by2[j]);
      float bxx = fminf(bx2[i], bx2[j]);
      float hh = fmaxf(byy - ty, 0.0f);
      float ww = fmaxf(bxx - tx, 0.0f);
      float inter = hh * ww;
      float iou = inter / (sarea[i] + sarea[j] - inter);
      if (iou > NMS_THR) skeep[j] = 0;
    }
  }
  __syncthreads();
  keep_out[(size_t)(c - 1) * R_ROIS + sidx[tid]] = skeep[tid] ? 1.0f : 0.0f;
}

// ---------------------------------------------------------------- launch
extern "C" void kernel_launch(void* const* d_in, const int* in_sizes, int n_in,
                              void* d_out, int out_size, void* d_ws,
                              size_t ws_size, hipStream_t stream) {
  const float* h = (const float*)d_in[0];
  const float* rois = (const float*)d_in[1];
  const int* roi_indices = (const int*)d_in[2];
  const float* W1 = (const float*)d_in[3];
  const float* b1 = (const float*)d_in[4];
  const float* W2 = (const float*)d_in[5];
  const float* b2 = (const float*)d_in[6];
  const float* Wloc = (const float*)d_in[7];
  const float* bloc = (const float*)d_in[8];
  const float* Wscore = (const float*)d_in[9];
  const float* bscore = (const float*)d_in[10];
  float* out = (float*)d_out;

  char* ws = (char*)d_ws;
  size_t off = 0;
  bf16* pool_bf = (bf16*)(ws + off); off += (size_t)R_ROIS * POOL_DIM * 2;
  bf16* fc_bf = (bf16*)(ws + off);   off += (size_t)R_ROIS * FC_DIM * 2;
  float* fc7 = (float*)(ws + off);   off += (size_t)R_ROIS * FC_DIM * 4;
  float* WT = (float*)(ws + off);    off += (size_t)55 * FC_DIM * 4;
  float* part = (float*)(ws + off);
  size_t part_bytes_per_s = (size_t)R_ROIS * FC_DIM * 4;
  int S = (ws_size - off >= 4 * part_bytes_per_s) ? 4 : 2;

  roi_pool_kernel<<<R_ROIS, 256, 0, stream>>>(h, rois, roi_indices, pool_bf);
  whead_transpose<<<55, 256, 0, stream>>>(Wloc, Wscore, WT);

  // FC1: A=pool_bf [512,25088], B=W1 [25088,4096]
  gemm_mfma<<<dim3(4, 32, S), 256, 0, stream>>>(pool_bf, W1, part, POOL_DIM,
                                                POOL_DIM / S);
  reduce_bias_relu<<<(R_ROIS * FC_DIM) / 1024, 256, 0, stream>>>(
      part, b1, S, fc_bf, fc7 /* scratch, overwritten by FC2 reduce */);

  // FC2: A=fc_bf [512,4096], B=W2 [4096,4096]
  gemm_mfma<<<dim3(4, 32, S), 256, 0, stream>>>(fc_bf, W2, part, FC_DIM,
                                                FC_DIM / S);
  reduce_bias_relu<<<(R_ROIS * FC_DIM) / 1024, 256, 0, stream>>>(
      part, b2, S, fc_bf /* unused after */, fc7);

  head_kernel<<<R_ROIS, 256, 0, stream>>>(fc7, WT, bloc, bscore, rois, out);
  nms_kernel<<<10, 512, 0, stream>>>(out, out + OUT_PROB_OFF,
                                     out + OUT_KEEP_OFF);
}

// Round 3
// 1220.863 us; speedup vs baseline: 3.0841x; 1.2258x over previous
//
#include <hip/hip_runtime.h>
#include <cfloat>
#include <cmath>
#include <stdint.h>

#define R_ROIS 512
#define NCLS 11
#define FEAT_C 512
#define FEAT_H 37
#define FEAT_W 50
#define FEAT_HW (FEAT_H * FEAT_W) /* 1850 */
#define POOLSZ 7
#define POOL_DIM (FEAT_C * POOLSZ * POOLSZ) /* 25088 */
#define FC_DIM 4096
#define IMG_Hf 600.0f
#define IMG_Wf 800.0f
#define SPATIAL_SCALE 0.0625f
#define NMS_THR 0.3f
#define SCORE_THR 0.05f

#define OUT_PROB_OFF (R_ROIS * NCLS * 4)
#define OUT_KEEP_OFF (OUT_PROB_OFF + R_ROIS * NCLS)

typedef __bf16 bf16;
typedef __attribute__((ext_vector_type(8))) __bf16 v8bf;
typedef __attribute__((ext_vector_type(4))) __bf16 v4bf;
typedef __attribute__((ext_vector_type(4))) float f32x4;
typedef unsigned int u32;
typedef unsigned short u16;

__device__ __forceinline__ void gload_lds16(const void* g, void* l) {
  __builtin_amdgcn_global_load_lds(
      (const __attribute__((address_space(1))) u32*)(uintptr_t)g,
      (__attribute__((address_space(3))) u32*)(uintptr_t)l, 16, 0, 0);
}

// ------------------------------------------- feature transpose NCHW->HWC bf16
// featT[yx][c] = (bf16)feat[c][yx]; writes coalesced across c.
__global__ __launch_bounds__(512) void feat_transpose(
    const float* __restrict__ feat, u16* __restrict__ featT) {
  int yx = blockIdx.x;
  int c = threadIdx.x;
  float v = feat[(size_t)c * FEAT_HW + yx];
  featT[(size_t)yx * FEAT_C + c] = (u16)(__float_as_uint(v) >> 16) /* trunc? */;
}
// NOTE: bf16 cast must round-to-nearest-even, not truncate — do it properly:
__global__ __launch_bounds__(512) void feat_transpose_rne(
    const float* __restrict__ feat, u16* __restrict__ featT) {
  int yx = blockIdx.x;
  int c = threadIdx.x;
  float v = feat[(size_t)c * FEAT_HW + yx];
  bf16 b = (bf16)v;
  featT[(size_t)yx * FEAT_C + c] = *(u16*)&b;
}

// ---------------------------------------------------------------- ROI pool
// block = 1 roi, 256 threads; thread handles channels (2t, 2t+1) via one u32
// load per (y,x). Windows are wave-uniform. Results staged in LDS [c][bin]
// then copied out coalesced.
__global__ __launch_bounds__(256) void roi_pool_hwc(
    const u16* __restrict__ featT, const float* __restrict__ rois,
    const int* __restrict__ roi_idx, bf16* __restrict__ pool) {
  __shared__ u16 lds[POOL_DIM];  // [c*49 + bin], 50176 B
  int r = blockIdx.x;
  int tid = threadIdx.x;
  float y1 = rois[r * 4 + 0], x1 = rois[r * 4 + 1];
  float y2 = rois[r * 4 + 2], x2 = rois[r * 4 + 3];
  float sw = rintf(x1 * SPATIAL_SCALE), ew = rintf(x2 * SPATIAL_SCALE);
  float sh = rintf(y1 * SPATIAL_SCALE), eh = rintf(y2 * SPATIAL_SCALE);
  float rw = fmaxf(ew - sw + 1.0f, 1.0f);
  float rh = fmaxf(eh - sh + 1.0f, 1.0f);
  int hs[POOLSZ], he[POOLSZ], wsA[POOLSZ], weA[POOLSZ];
#pragma unroll
  for (int p = 0; p < POOLSZ; ++p) {
    float fp = (float)p;
    hs[p] = (int)fminf(fmaxf(floorf(fp * rh / 7.0f) + sh, 0.0f), (float)FEAT_H);
    he[p] = (int)fminf(fmaxf(ceilf((fp + 1.0f) * rh / 7.0f) + sh, 0.0f), (float)FEAT_H);
    wsA[p] = (int)fminf(fmaxf(floorf(fp * rw / 7.0f) + sw, 0.0f), (float)FEAT_W);
    weA[p] = (int)fminf(fmaxf(ceilf((fp + 1.0f) * rw / 7.0f) + sw, 0.0f), (float)FEAT_W);
  }
  const u32* fb = (const u32*)(featT + (size_t)roi_idx[r] * FEAT_HW * FEAT_C) + tid;
#pragma unroll
  for (int p = 0; p < POOLSZ; ++p) {
    int h0 = hs[p], h1 = he[p];
#pragma unroll
    for (int q = 0; q < POOLSZ; ++q) {
      int w0 = wsA[q], w1 = weA[q];
      float m0, m1;
      if (h1 > h0 && w1 > w0) {
        m0 = -FLT_MAX; m1 = -FLT_MAX;
        for (int y = h0; y < h1; ++y) {
          const u32* row = fb + ((size_t)(y * FEAT_W) << 8);  // *512 ch /2 per u32
          for (int x = w0; x < w1; ++x) {
            u32 u = row[(size_t)x << 8];
            m0 = fmaxf(m0, __uint_as_float(u << 16));
            m1 = fmaxf(m1, __uint_as_float(u & 0xffff0000u));
          }
        }
      } else {
        m0 = 0.0f; m1 = 0.0f;
      }
      int bin = p * 7 + q;
      lds[(2 * tid) * 49 + bin] = (u16)(__float_as_uint(m0) >> 16);
      lds[(2 * tid + 1) * 49 + bin] = (u16)(__float_as_uint(m1) >> 16);
    }
  }
  __syncthreads();
  bf16* po = pool + (size_t)r * POOL_DIM;
  for (int idx = tid * 8; idx < POOL_DIM; idx += 2048)
    *(v8bf*)(po + idx) = *(const v8bf*)(lds + idx);
}

// ------------------------------------------------- head weight transpose
__global__ __launch_bounds__(256) void whead_transpose(
    const float* __restrict__ Wloc, const float* __restrict__ Wscore,
    float* __restrict__ WT) {
  int o = blockIdx.x;
  for (int k = threadIdx.x; k < FC_DIM; k += 256) {
    float v = (o < 44) ? Wloc[(size_t)k * 44 + o]
                       : Wscore[(size_t)k * 11 + (o - 44)];
    WT[(size_t)o * FC_DIM + k] = v;
  }
}

// ---------------------------------------------------------------- MFMA GEMM
__global__ __launch_bounds__(256) void gemm_mfma(
    const bf16* __restrict__ A, const float* __restrict__ B,
    float* __restrict__ part, int K, int Kper) {
  __shared__ __align__(16) bf16 As[128 * 32];   // [m][k], unpadded (DMA dest)
  __shared__ __align__(16) bf16 Bs[128 * 40];   // [n][k], stride 40 (pad 8)
  int tid = threadIdx.x;
  int bm = blockIdx.x * 128;
  int bn = blockIdx.y * 128;
  int s = blockIdx.z;
  int kbeg = s * Kper;
  int kend = kbeg + Kper;
  int lane = tid & 63;
  int wave = tid >> 6;
  int wm = (wave >> 1) * 64;
  int wn = (wave & 1) * 64;

  f32x4 acc[4][4];
#pragma unroll
  for (int i = 0; i < 4; ++i)
#pragma unroll
    for (int j = 0; j < 4; ++j) acc[i][j] = (f32x4){0.f, 0.f, 0.f, 0.f};

  int arow = tid >> 2;
  int acol = (tid & 3) * 8;
  const bf16* Ag0 = A + (size_t)(bm + arow) * K + acol;
  const bf16* Ag1 = A + (size_t)(bm + 64 + arow) * K + acol;
  bf16* Ad0 = As + tid * 8;
  bf16* Ad1 = As + 2048 + tid * 8;

  int nB = tid & 127;
  int khB = (tid >> 7) * 16;
  const float* Bg = B + (size_t)khB * FC_DIM + bn + nB;
  bf16* Bd = Bs + nB * 40 + khB;

  for (int k0 = kbeg; k0 < kend; k0 += 32) {
    __syncthreads();
    gload_lds16(Ag0 + k0, Ad0);
    gload_lds16(Ag1 + k0, Ad1);
    const float* bp = Bg + (size_t)k0 * FC_DIM;
    float bv[16];
#pragma unroll
    for (int j = 0; j < 16; ++j) bv[j] = bp[(size_t)j * FC_DIM];
    v8bf blo, bhi;
#pragma unroll
    for (int j = 0; j < 8; ++j) blo[j] = (bf16)bv[j];
#pragma unroll
    for (int j = 0; j < 8; ++j) bhi[j] = (bf16)bv[8 + j];
    *(v8bf*)(Bd) = blo;
    *(v8bf*)(Bd + 8) = bhi;
    __syncthreads();

    v8bf af[4], bfr[4];
#pragma unroll
    for (int i = 0; i < 4; ++i)
      af[i] = *(const v8bf*)(As + (wm + i * 16 + (lane & 15)) * 32 +
                             (lane >> 4) * 8);
#pragma unroll
    for (int j = 0; j < 4; ++j)
      bfr[j] = *(const v8bf*)(Bs + (wn + j * 16 + (lane & 15)) * 40 +
                              (lane >> 4) * 8);
#pragma unroll
    for (int i = 0; i < 4; ++i)
#pragma unroll
      for (int j = 0; j < 4; ++j)
        acc[i][j] = __builtin_amdgcn_mfma_f32_16x16x32_bf16(af[i], bfr[j],
                                                            acc[i][j], 0, 0, 0);
  }

  int cn = lane & 15;
  int rq = (lane >> 4) * 4;
  float* po = part + ((size_t)s * R_ROIS + bm + wm + rq) * FC_DIM + bn + wn + cn;
#pragma unroll
  for (int i = 0; i < 4; ++i)
#pragma unroll
    for (int r = 0; r < 4; ++r) {
      float* pr = po + (size_t)(i * 16 + r) * FC_DIM;
#pragma unroll
      for (int j = 0; j < 4; ++j) pr[j * 16] = acc[i][j][r];
    }
}

// ------------------------------------------------- split-K reduce + bias+relu
__global__ __launch_bounds__(256) void reduce_bias_relu(
    const float* __restrict__ part, const float* __restrict__ bias, int S,
    bf16* __restrict__ out_bf, float* __restrict__ out_f32) {
  int idx = (blockIdx.x * 256 + threadIdx.x) * 4;
  f32x4 sum = *(const f32x4*)(part + idx);
  for (int s = 1; s < S; ++s)
    sum += *(const f32x4*)(part + (size_t)s * R_ROIS * FC_DIM + idx);
  int n = idx & (FC_DIM - 1);
  f32x4 b = *(const f32x4*)(bias + n);
  sum += b;
#pragma unroll
  for (int c = 0; c < 4; ++c) sum[c] = fmaxf(sum[c], 0.0f);
  *(f32x4*)(out_f32 + idx) = sum;
  v4bf h;
#pragma unroll
  for (int c = 0; c < 4; ++c) h[c] = (bf16)sum[c];
  *(v4bf*)(out_bf + idx) = h;
}

// ---------------------------------------------------------------- head
__global__ __launch_bounds__(256) void head_kernel(
    const float* __restrict__ fc7, const float* __restrict__ WT,
    const float* __restrict__ bloc, const float* __restrict__ bscore,
    const float* __restrict__ rois, float* __restrict__ out) {
  __shared__ float row[FC_DIM];
  __shared__ float outv[64];
  int r = blockIdx.x;
  int tid = threadIdx.x;
  for (int k = tid * 4; k < FC_DIM; k += 1024)
    *(float4*)(row + k) = *(const float4*)(fc7 + (size_t)r * FC_DIM + k);
  __syncthreads();
  int wave = tid >> 6, lane = tid & 63;
  for (int o = wave; o < 55; o += 4) {
    const float* w = WT + (size_t)o * FC_DIM;
    float p = 0.0f;
    for (int k = lane * 4; k < FC_DIM; k += 256) {
      float4 a = *(const float4*)(row + k);
      float4 b = *(const float4*)(w + k);
      p += a.x * b.x + a.y * b.y + a.z * b.z + a.w * b.w;
    }
#pragma unroll
    for (int off = 32; off; off >>= 1) p += __shfl_down(p, off);
    if (lane == 0) outv[o] = p;
  }
  __syncthreads();
  if (tid == 0) {
    float sarr[NCLS];
    float m = -FLT_MAX;
#pragma unroll
    for (int j = 0; j < NCLS; ++j) {
      sarr[j] = outv[44 + j] + bscore[j];
      m = fmaxf(m, sarr[j]);
    }
    float sum = 0.0f;
#pragma unroll
    for (int j = 0; j < NCLS; ++j) {
      sarr[j] = expf(sarr[j] - m);
      sum += sarr[j];
    }
    float inv = 1.0f / sum;
#pragma unroll
    for (int j = 0; j < NCLS; ++j)
      out[OUT_PROB_OFF + r * NCLS + j] = sarr[j] * inv;
    float y1 = rois[r * 4 + 0], x1 = rois[r * 4 + 1];
    float y2 = rois[r * 4 + 2], x2 = rois[r * 4 + 3];
    float shh = y2 - y1, sww = x2 - x1;
    float cy = y1 + 0.5f * shh, cx = x1 + 0.5f * sww;
    const float STD[4] = {0.1f, 0.1f, 0.2f, 0.2f};
    for (int c = 0; c < NCLS; ++c) {
      float l0 = (outv[c * 4 + 0] + bloc[c * 4 + 0]) * STD[0];
      float l1 = (outv[c * 4 + 1] + bloc[c * 4 + 1]) * STD[1];
      float l2 = (outv[c * 4 + 2] + bloc[c * 4 + 2]) * STD[2];
      float l3 = (outv[c * 4 + 3] + bloc[c * 4 + 3]) * STD[3];
      float ncy = l0 * shh + cy, ncx = l1 * sww + cx;
      float nh = expf(l2) * shh, nw = expf(l3) * sww;
      out[r * 44 + c * 4 + 0] = fminf(fmaxf(ncy - 0.5f * nh, 0.0f), IMG_Hf);
      out[r * 44 + c * 4 + 1] = fminf(fmaxf(ncx - 0.5f * nw, 0.0f), IMG_Wf);
      out[r * 44 + c * 4 + 2] = fminf(fmaxf(ncy + 0.5f * nh, 0.0f), IMG_Hf);
      out[r * 44 + c * 4 + 3] = fminf(fmaxf(ncx + 0.5f * nw, 0.0f), IMG_Wf);
    }
  }
}

// ---------------------------------------------------------------- NMS
__device__ __forceinline__ bool key_lt(float ka, int ia, float kb, int ib) {
  return (ka < kb) || (ka == kb && ia < ib);
}

__global__ __launch_bounds__(512) void nms_kernel(
    const float* __restrict__ cls_bbox, const float* __restrict__ prob,
    float* __restrict__ keep_out) {
  int c = blockIdx.x + 1;
  int tid = threadIdx.x;
  __shared__ float skey[512];
  __shared__ int sidx[512];
  __shared__ float by1[512], bx1[512], by2[512], bx2[512], sarea[512];
  __shared__ int skeep[512];
  float s = prob[tid * NCLS + c];
  skey[tid] = (s > SCORE_THR) ? -s : INFINITY;
  sidx[tid] = tid;
  for (int k = 2; k <= 512; k <<= 1) {
    for (int j = k >> 1; j > 0; j >>= 1) {
      __syncthreads();
      int ixj = tid ^ j;
      if (ixj > tid) {
        float k1 = skey[tid], k2 = skey[ixj];
        int i1 = sidx[tid], i2 = sidx[ixj];
        bool up = ((tid & k) == 0);
        bool do_swap = up ? key_lt(k2, i2, k1, i1) : key_lt(k1, i1, k2, i2);
        if (do_swap) {
          skey[tid] = k2; skey[ixj] = k1;
          sidx[tid] = i2; sidx[ixj] = i1;
        }
      }
    }
  }
  __syncthreads();
  {
    int r = sidx[tid];
    float yy1 = cls_bbox[r * 44 + c * 4 + 0];
    float xx1 = cls_bbox[r * 44 + c * 4 + 1];
    float yy2 = cls_bbox[r * 44 + c * 4 + 2];
    float xx2 = cls_bbox[r * 44 + c * 4 + 3];
    by1[tid] = yy1; bx1[tid] = xx1; by2[tid] = yy2; bx2[tid] = xx2;
    sarea[tid] = (yy2 - yy1) * (xx2 - xx1);
    skeep[tid] = (skey[tid] != INFINITY) ? 1 : 0;
  }
  for (int i = 0; i < 511; ++i) {
    __syncthreads();
    if (!skeep[i]) continue;
    int j = tid;
    if (j > i && skeep[j]) {
      float ty = fmaxf(by1[i], by1[j]);
      float tx = fmaxf(bx1[i], bx1[j]);
      float byy = fminf(by2[i], by2[j]);
      float bxx = fminf(bx2[i], bx2[j]);
      float hh = fmaxf(byy - ty, 0.0f);
      float ww = fmaxf(bxx - tx, 0.0f);
      float inter = hh * ww;
      float iou = inter / (sarea[i] + sarea[j] - inter);
      if (iou > NMS_THR) skeep[j] = 0;
    }
  }
  __syncthreads();
  keep_out[(size_t)(c - 1) * R_ROIS + sidx[tid]] = skeep[tid] ? 1.0f : 0.0f;
}

// ---------------------------------------------------------------- launch
extern "C" void kernel_launch(void* const* d_in, const int* in_sizes, int n_in,
                              void* d_out, int out_size, void* d_ws,
                              size_t ws_size, hipStream_t stream) {
  const float* h = (const float*)d_in[0];
  const float* rois = (const float*)d_in[1];
  const int* roi_indices = (const int*)d_in[2];
  const float* W1 = (const float*)d_in[3];
  const float* b1 = (const float*)d_in[4];
  const float* W2 = (const float*)d_in[5];
  const float* b2 = (const float*)d_in[6];
  const float* Wloc = (const float*)d_in[7];
  const float* bloc = (const float*)d_in[8];
  const float* Wscore = (const float*)d_in[9];
  const float* bscore = (const float*)d_in[10];
  float* out = (float*)d_out;

  char* ws = (char*)d_ws;
  size_t off = 0;
  bf16* pool_bf = (bf16*)(ws + off); off += (size_t)R_ROIS * POOL_DIM * 2;
  bf16* fc_bf = (bf16*)(ws + off);   off += (size_t)R_ROIS * FC_DIM * 2;
  float* fc7 = (float*)(ws + off);   off += (size_t)R_ROIS * FC_DIM * 4;
  float* WT = (float*)(ws + off);    off += (size_t)55 * FC_DIM * 4;
  u16* featT = (u16*)(ws + off);     off += (size_t)FEAT_HW * FEAT_C * 2;
  float* part = (float*)(ws + off);
  size_t part_bytes_per_s = (size_t)R_ROIS * FC_DIM * 4;
  int S = (ws_size - off >= 4 * part_bytes_per_s) ? 4 : 2;

  feat_transpose_rne<<<FEAT_HW, 512, 0, stream>>>(h, featT);
  whead_transpose<<<55, 256, 0, stream>>>(Wloc, Wscore, WT);
  roi_pool_hwc<<<R_ROIS, 256, 0, stream>>>(featT, rois, roi_indices, pool_bf);

  gemm_mfma<<<dim3(4, 32, S), 256, 0, stream>>>(pool_bf, W1, part, POOL_DIM,
                                                POOL_DIM / S);
  reduce_bias_relu<<<(R_ROIS * FC_DIM) / 1024, 256, 0, stream>>>(
      part, b1, S, fc_bf, fc7);

  gemm_mfma<<<dim3(4, 32, S), 256, 0, stream>>>(fc_bf, W2, part, FC_DIM,
                                                FC_DIM / S);
  reduce_bias_relu<<<(R_ROIS * FC_DIM) / 1024, 256, 0, stream>>>(
      part, b2, S, fc_bf, fc7);

  head_kernel<<<R_ROIS, 256, 0, stream>>>(fc7, WT, bloc, bscore, rois, out);
  nms_kernel<<<10, 512, 0, stream>>>(out, out + OUT_PROB_OFF,
                                     out + OUT_KEEP_OFF);
}